// Round 1
// baseline (2811.891 us; speedup 1.0000x reference)
//
#include <hip/hip_runtime.h>

// Sinkhorn divergence (geomloss 'sinkhorn', p=2, blur=0.05, diameter=4, scaling=0.5, debias)
// B=2, N=M=4096, D=3, fp32. Strategy: never materialize C; 11 fused softmin
// launches (each = 4 independent softmins x 2 batches) + 1 reduce.
// Potentials double-buffered in d_ws (2 sets x 4 arrays x [2*4096] f32 = 256 KB).
//
// softmin(eps,C,h)[i] = 0.5*|x_i|^2 - eps*ln2*( m + log2 s ),  (m,s)=LSE2 over j of
//   V[j] = T[j] + x_i . (y_j * log2e/eps),   T[j] = (hc + (pot[j]-0.5|y_j|^2)/eps)*log2e
// where hc = -ln(4096) (a_log == b_log since N==M).

#define NPT 4096
#define BPT 64                              // blocks per table
#define BLOCK 512
#define WAVES (BLOCK / 64)                  // 8
#define ROWS_PER_BLOCK (NPT / BPT)          // 64
#define ROWS_PER_WAVE (ROWS_PER_BLOCK / WAVES)  // 8
#define CHUNK 16
#define NCHUNK (NPT / 64 / CHUNK)           // 4

__device__ __constant__ const float kLog2e = 1.4426950408889634f;
__device__ __constant__ const float kLn2   = 0.6931471805599453f;

struct SoftminArgs {
  const float* xpts[4];   // row-side points base [2*4096*3]
  const float* ypts[4];   // col-side points base
  const float* pot[4];    // col-side dual potential (cur set)
  const float* oldv[4];   // old value of the output potential (cur set)
  float* outp[4];         // output potential (nxt set)
  float eps;
  int use_pot;            // 0 for init launch
  int use_avg;            // 1 for the 9 loop launches
};

__global__ __launch_bounds__(BLOCK, 4) void softmin4(SoftminArgs A) {
  __shared__ float4 tab[NPT];               // 64 KB
  const int bid   = blockIdx.x;
  const int table = bid / BPT;              // 0..7
  const int chunk = bid % BPT;
  const int task  = table >> 1;
  const int batch = table & 1;

  const float* xp = A.xpts[task] + batch * NPT * 3;
  const float* yp = A.ypts[task] + batch * NPT * 3;
  const float* pp = A.pot[task]  + batch * NPT;
  const float* ov = A.oldv[task] + batch * NPT;
  float*       op = A.outp[task] + batch * NPT;

  const float inv_eps = 1.0f / A.eps;
  const float sY      = inv_eps * kLog2e;
  const float hc      = -8.317766166719343f;   // -ln(4096)

  // Stage col-side table: (y*sY, T[j])
  for (int j = threadIdx.x; j < NPT; j += BLOCK) {
    float y0 = yp[3 * j + 0], y1 = yp[3 * j + 1], y2 = yp[3 * j + 2];
    float p  = A.use_pot ? pp[j] : 0.0f;
    float T  = (hc + (p - 0.5f * (y0 * y0 + y1 * y1 + y2 * y2)) * inv_eps) * kLog2e;
    tab[j] = make_float4(y0 * sY, y1 * sY, y2 * sY, T);
  }
  __syncthreads();

  const int wave = threadIdx.x >> 6;
  const int lane = threadIdx.x & 63;

  for (int t = 0; t < ROWS_PER_WAVE; ++t) {
    int row = __builtin_amdgcn_readfirstlane(chunk * ROWS_PER_BLOCK + wave * ROWS_PER_WAVE + t);
    const float x0 = xp[3 * row + 0], x1 = xp[3 * row + 1], x2 = xp[3 * row + 2];

    float m = -__builtin_inff();
    float s = 0.0f;
#pragma unroll
    for (int c = 0; c < NCHUNK; ++c) {
      float v[CHUNK];
      float cm = -__builtin_inff();
#pragma unroll
      for (int k = 0; k < CHUNK; ++k) {
        float4 tv = tab[(c * CHUNK + k) * 64 + lane];
        float vv = fmaf(x0, tv.x, fmaf(x1, tv.y, fmaf(x2, tv.z, tv.w)));
        v[k] = vv;
        cm = fmaxf(cm, vv);
      }
      float mn = fmaxf(m, cm);
      s *= __builtin_amdgcn_exp2f(m - mn);     // m=-inf first chunk -> exp2(-inf)=0, s stays 0
      float cs = 0.0f;
#pragma unroll
      for (int k = 0; k < CHUNK; ++k) cs += __builtin_amdgcn_exp2f(v[k] - mn);
      s += cs;
      m = mn;
    }

    // cross-lane (m,s) butterfly over 64 lanes
#pragma unroll
    for (int off = 32; off >= 1; off >>= 1) {
      float mo = __shfl_xor(m, off, 64);
      float so = __shfl_xor(s, off, 64);
      float mn = fmaxf(m, mo);
      s = s * __builtin_amdgcn_exp2f(m - mn) + so * __builtin_amdgcn_exp2f(mo - mn);
      m = mn;
    }

    float r = 0.5f * (x0 * x0 + x1 * x1 + x2 * x2)
            - A.eps * kLn2 * (m + __builtin_amdgcn_logf(s));
    if (A.use_avg) r = 0.5f * (ov[row] + r);
    if (lane == 0) op[row] = r;
  }
}

// F = (1/4096) * sum_{batch,i} [ (b_x - a_x) + (a_y - b_y) ]
__global__ __launch_bounds__(256) void reduce_k(const float* W, float* out) {
  const float* bx = W + 0 * 8192;
  const float* ay = W + 1 * 8192;
  const float* ax = W + 2 * 8192;
  const float* by = W + 3 * 8192;
  float acc = 0.0f;
  for (int i = threadIdx.x; i < 8192; i += 256)
    acc += (bx[i] - ax[i]) + (ay[i] - by[i]);
#pragma unroll
  for (int off = 32; off >= 1; off >>= 1) acc += __shfl_xor(acc, off, 64);
  __shared__ float red[4];
  const int wave = threadIdx.x >> 6, lane = threadIdx.x & 63;
  if (lane == 0) red[wave] = acc;
  __syncthreads();
  if (threadIdx.x == 0)
    out[0] = (red[0] + red[1] + red[2] + red[3]) * (1.0f / 4096.0f);
}

extern "C" void kernel_launch(void* const* d_in, const int* in_sizes, int n_in,
                              void* d_out, int out_size, void* d_ws, size_t ws_size,
                              hipStream_t stream) {
  const float* x = (const float*)d_in[0];   // true_data
  const float* y = (const float*)d_in[1];   // particles
  float* out = (float*)d_out;
  float* W   = (float*)d_ws;
  float* S[2] = { W, W + 4 * 8192 };        // two potential sets, arr order: b_x,a_y,a_x,b_y

  // eps schedule: [16] + exp(arange(2ln4, 2ln0.05, 2ln0.5)) + [0.0025]
  static const float eps_list[9] = { 16.0f, 16.0f, 4.0f, 1.0f, 0.25f,
                                     0.0625f, 0.015625f, 0.00390625f, 0.0025f };

  auto make_args = [&](int cur, int nxt, float eps, int use_pot, int use_avg) {
    SoftminArgs A;
    const float* rows[4] = { x, y, x, y };  // b_x<-C_xy, a_y<-C_yx, a_x<-C_xx, b_y<-C_yy
    const float* cols[4] = { y, x, x, y };
    const int pidx[4] = { 1, 0, 2, 3 };     // pot used: a_y, b_x, a_x, b_y
    for (int t = 0; t < 4; ++t) {
      A.xpts[t] = rows[t];
      A.ypts[t] = cols[t];
      A.pot[t]  = S[cur] + pidx[t] * 8192;
      A.oldv[t] = S[cur] + t * 8192;
      A.outp[t] = S[nxt] + t * 8192;
    }
    A.eps = eps; A.use_pot = use_pot; A.use_avg = use_avg;
    return A;
  };

  dim3 grid(8 * BPT), block(BLOCK);

  // init: writes set0, reads no potentials
  {
    SoftminArgs A = make_args(0, 0, eps_list[0], 0, 0);
    softmin4<<<grid, block, 0, stream>>>(A);
  }
  int cur = 0;
  // 9 symmetrized eps-scaling iterations (averaged updates)
  for (int k = 0; k < 9; ++k) {
    int nxt = 1 - cur;
    SoftminArgs A = make_args(cur, nxt, eps_list[k], 1, 1);
    softmin4<<<grid, block, 0, stream>>>(A);
    cur = nxt;
  }
  // final extrapolation (no averaging), eps = blur^2
  {
    int nxt = 1 - cur;
    SoftminArgs A = make_args(cur, nxt, eps_list[8], 1, 0);
    softmin4<<<grid, block, 0, stream>>>(A);
    cur = nxt;
  }
  reduce_k<<<1, 256, 0, stream>>>(S[cur], out);
}

// Round 2
// 467.004 us; speedup vs baseline: 6.0211x; 6.0211x over previous
//
#include <hip/hip_runtime.h>

// Sinkhorn divergence (geomloss 'sinkhorn', p=2, blur=0.05, diameter=4, scaling=0.5, debias)
// B=2, N=M=4096, D=3, fp32. 11 fused softmin launches (4 softmins x 2 batches each) + reduce.
// R2: killed the v[16] scratch spill (was 1 GB HBM traffic/dispatch): col chunk 16->4,
//     and 4 rows share each LDS read (row x's are wave-uniform scalars) -> LDS traffic /4.

#define NPT 4096
#define BPT 64                              // blocks per table
#define BLOCK 512
#define RPB 64                              // rows per block
#define RPW 8                               // rows per wave
#define R 4                                 // rows per group (share LDS reads)
#define C 4                                 // column chunk (x 64 lanes)

__device__ __constant__ const float kLog2e = 1.4426950408889634f;
__device__ __constant__ const float kLn2   = 0.6931471805599453f;

struct SoftminArgs {
  const float* xpts[4];   // row-side points base [2*4096*3]
  const float* ypts[4];   // col-side points base
  const float* pot[4];    // col-side dual potential (cur set)
  const float* oldv[4];   // old value of the output potential (cur set)
  float* outp[4];         // output potential (nxt set)
  float eps;
  int use_pot;            // 0 for init launch
  int use_avg;            // 1 for the 9 loop launches
};

__global__ __launch_bounds__(BLOCK, 4) void softmin4(SoftminArgs A) {
  __shared__ float4 tab[NPT];               // 64 KB -> 2 blocks/CU
  const int bid    = blockIdx.x;
  const int table  = bid >> 6;              // /BPT, 0..7
  const int blkrow = bid & (BPT - 1);
  const int task   = table >> 1;
  const int batch  = table & 1;

  const float* xp = A.xpts[task] + batch * NPT * 3;
  const float* yp = A.ypts[task] + batch * NPT * 3;
  const float* pp = A.pot[task]  + batch * NPT;
  const float* ov = A.oldv[task] + batch * NPT;
  float*       op = A.outp[task] + batch * NPT;

  const float inv_eps = 1.0f / A.eps;
  const float sY      = inv_eps * kLog2e;
  const float hc      = -8.317766166719343f;   // -ln(4096)

  // Stage col-side table: (y*sY, T[j]), T = (hc + (pot - 0.5|y|^2)/eps)*log2e
  for (int j = threadIdx.x; j < NPT; j += BLOCK) {
    float y0 = yp[3 * j + 0], y1 = yp[3 * j + 1], y2 = yp[3 * j + 2];
    float p  = A.use_pot ? pp[j] : 0.0f;
    float T  = (hc + (p - 0.5f * (y0 * y0 + y1 * y1 + y2 * y2)) * inv_eps) * kLog2e;
    tab[j] = make_float4(y0 * sY, y1 * sY, y2 * sY, T);
  }
  __syncthreads();

  const int wave = threadIdx.x >> 6;
  const int lane = threadIdx.x & 63;

#pragma unroll
  for (int g = 0; g < RPW / R; ++g) {
    const int rowbase = blkrow * RPB + wave * RPW + g * R;
    float x0[R], x1[R], x2[R], m[R], s[R];
#pragma unroll
    for (int r = 0; r < R; ++r) {
      int row = __builtin_amdgcn_readfirstlane(rowbase + r);
      x0[r] = xp[3 * row + 0];
      x1[r] = xp[3 * row + 1];
      x2[r] = xp[3 * row + 2];
      m[r] = -__builtin_inff();
      s[r] = 0.0f;
    }

#pragma unroll 2
    for (int cc = 0; cc < NPT / 64; cc += C) {
      float4 tv[C];
#pragma unroll
      for (int c = 0; c < C; ++c) tv[c] = tab[(cc + c) * 64 + lane];

      float v[R][C];
      float cm[R];
#pragma unroll
      for (int r = 0; r < R; ++r) cm[r] = -__builtin_inff();
#pragma unroll
      for (int c = 0; c < C; ++c)
#pragma unroll
        for (int r = 0; r < R; ++r) {
          float vv = fmaf(x0[r], tv[c].x,
                     fmaf(x1[r], tv[c].y,
                     fmaf(x2[r], tv[c].z, tv[c].w)));
          v[r][c] = vv;
          cm[r] = fmaxf(cm[r], vv);
        }
#pragma unroll
      for (int r = 0; r < R; ++r) {
        float mn = fmaxf(m[r], cm[r]);
        s[r] *= __builtin_amdgcn_exp2f(m[r] - mn);   // m=-inf first iter -> 0, s stays 0
        float cs = 0.0f;
#pragma unroll
        for (int c = 0; c < C; ++c) cs += __builtin_amdgcn_exp2f(v[r][c] - mn);
        s[r] += cs;
        m[r] = mn;
      }
    }

#pragma unroll
    for (int r = 0; r < R; ++r) {
      float mm = m[r], ss = s[r];
#pragma unroll
      for (int off = 32; off >= 1; off >>= 1) {
        float mo = __shfl_xor(mm, off, 64);
        float so = __shfl_xor(ss, off, 64);
        float mn = fmaxf(mm, mo);
        ss = ss * __builtin_amdgcn_exp2f(mm - mn) + so * __builtin_amdgcn_exp2f(mo - mn);
        mm = mn;
      }
      int row = rowbase + r;
      float res = 0.5f * (x0[r] * x0[r] + x1[r] * x1[r] + x2[r] * x2[r])
                - A.eps * kLn2 * (mm + __builtin_amdgcn_logf(ss));
      if (A.use_avg) res = 0.5f * (ov[row] + res);
      if (lane == 0) op[row] = res;
    }
  }
}

// F = (1/4096) * sum_{batch,i} [ (b_x - a_x) + (a_y - b_y) ]
__global__ __launch_bounds__(256) void reduce_k(const float* W, float* out) {
  const float* bx = W + 0 * 8192;
  const float* ay = W + 1 * 8192;
  const float* ax = W + 2 * 8192;
  const float* by = W + 3 * 8192;
  float acc = 0.0f;
  for (int i = threadIdx.x; i < 8192; i += 256)
    acc += (bx[i] - ax[i]) + (ay[i] - by[i]);
#pragma unroll
  for (int off = 32; off >= 1; off >>= 1) acc += __shfl_xor(acc, off, 64);
  __shared__ float red[4];
  const int wave = threadIdx.x >> 6, lane = threadIdx.x & 63;
  if (lane == 0) red[wave] = acc;
  __syncthreads();
  if (threadIdx.x == 0)
    out[0] = (red[0] + red[1] + red[2] + red[3]) * (1.0f / 4096.0f);
}

extern "C" void kernel_launch(void* const* d_in, const int* in_sizes, int n_in,
                              void* d_out, int out_size, void* d_ws, size_t ws_size,
                              hipStream_t stream) {
  const float* x = (const float*)d_in[0];   // true_data
  const float* y = (const float*)d_in[1];   // particles
  float* out = (float*)d_out;
  float* W   = (float*)d_ws;
  float* S[2] = { W, W + 4 * 8192 };        // two potential sets, arr order: b_x,a_y,a_x,b_y

  // eps schedule: [16] + exp(arange(2ln4, 2ln0.05, 2ln0.5)) + [0.0025]
  static const float eps_list[9] = { 16.0f, 16.0f, 4.0f, 1.0f, 0.25f,
                                     0.0625f, 0.015625f, 0.00390625f, 0.0025f };

  auto make_args = [&](int cur, int nxt, float eps, int use_pot, int use_avg) {
    SoftminArgs A;
    const float* rows[4] = { x, y, x, y };  // b_x<-C_xy, a_y<-C_yx, a_x<-C_xx, b_y<-C_yy
    const float* cols[4] = { y, x, x, y };
    const int pidx[4] = { 1, 0, 2, 3 };     // pot used: a_y, b_x, a_x, b_y
    for (int t = 0; t < 4; ++t) {
      A.xpts[t] = rows[t];
      A.ypts[t] = cols[t];
      A.pot[t]  = S[cur] + pidx[t] * 8192;
      A.oldv[t] = S[cur] + t * 8192;
      A.outp[t] = S[nxt] + t * 8192;
    }
    A.eps = eps; A.use_pot = use_pot; A.use_avg = use_avg;
    return A;
  };

  dim3 grid(8 * BPT), block(BLOCK);

  // init: writes set0, reads no potentials
  {
    SoftminArgs A = make_args(0, 0, eps_list[0], 0, 0);
    softmin4<<<grid, block, 0, stream>>>(A);
  }
  int cur = 0;
  // 9 symmetrized eps-scaling iterations (averaged updates)
  for (int k = 0; k < 9; ++k) {
    int nxt = 1 - cur;
    SoftminArgs A = make_args(cur, nxt, eps_list[k], 1, 1);
    softmin4<<<grid, block, 0, stream>>>(A);
    cur = nxt;
  }
  // final extrapolation (no averaging), eps = blur^2
  {
    int nxt = 1 - cur;
    SoftminArgs A = make_args(cur, nxt, eps_list[8], 1, 0);
    softmin4<<<grid, block, 0, stream>>>(A);
    cur = nxt;
  }
  reduce_k<<<1, 256, 0, stream>>>(S[cur], out);
}

// Round 3
// 365.394 us; speedup vs baseline: 7.6955x; 1.2781x over previous
//
#include <hip/hip_runtime.h>

// Sinkhorn divergence (geomloss 'sinkhorn', p=2, blur=0.05, diameter=4, scaling=0.5, debias)
// B=2, N=M=4096, D=3, fp32.
// R3: MFMA offload. V[j,i] = T_j + x_i . (y_j*log2e/eps) computed entirely by
// mfma_f32_16x16x32_bf16 via K-slot packing (split-bf16 products + 3-split T against B=1),
// leaving only {max, sub, exp2, add} per element on the VALU/trans pipes.
// Partial (m,s) per column-part; finalization (avg + pot) deferred into the NEXT
// launch's staging pass (finalized-pot double buffer), reduce finalizes the last launch.

typedef __attribute__((ext_vector_type(8))) short short8;
typedef __attribute__((ext_vector_type(8))) __bf16 bf16x8;
typedef __attribute__((ext_vector_type(4))) float f32x4;

#define NPT 4096
#define BLOCK 512
#define COLS 1024           // columns per block (one part)
#define NPARTS 4
#define ROWS_PER_BLOCK 256  // 8 waves x 2 rowsets x 16
#define NRC 16              // rowchunks
#define EXP2 __builtin_amdgcn_exp2f
#define LOG2 __builtin_amdgcn_logf
#define KLOG2E 1.4426950408889634f
#define KLN2 0.6931471805599453f

__device__ inline unsigned short f2bf(float f) {
  unsigned u = __float_as_uint(f);
  return (unsigned short)((u + 0x7FFF + ((u >> 16) & 1)) >> 16);
}
__device__ inline float bf2f(unsigned short h) {
  return __uint_as_float(((unsigned)h) << 16);
}

struct SArgs {
  const float* rowPts[4];
  const float* colPts[4];
  const float2* Pprev;   // partials from previous launch [8 tbl][4 part][4096] (m,s)
  float2* Pcur;
  const float* Fprev;    // finalized potentials [8 tbl][4096]
  float* Fcur;
  float eps, epsPrev;
  int usePot, avgPrev;
};

__device__ inline void lse_merge8(float& m, float& s, f32x4 ca, f32x4 cb) {
  float cm = fmaxf(fmaxf(fmaxf(ca.x, ca.y), fmaxf(ca.z, ca.w)),
                   fmaxf(fmaxf(cb.x, cb.y), fmaxf(cb.z, cb.w)));
  float mn = fmaxf(m, cm);
  float sc = EXP2(m - mn);             // m=-inf first iter -> 0
  float cs = (EXP2(ca.x - mn) + EXP2(ca.y - mn)) + (EXP2(ca.z - mn) + EXP2(ca.w - mn))
           + (EXP2(cb.x - mn) + EXP2(cb.y - mn)) + (EXP2(cb.z - mn) + EXP2(cb.w - mn));
  s = fmaf(s, sc, cs);
  m = mn;
}

__global__ __launch_bounds__(BLOCK, 2) void softmin_mfma(SArgs A) {
  __shared__ short8 fragA0[COLS];   // k0..7  per column
  __shared__ short8 fragA1[COLS];   // k8..15 per column

  const int bid  = blockIdx.x;
  const int tbl  = bid >> 6;          // 0..7 = task*2+batch
  const int task = tbl >> 1, batch = tbl & 1;
  const int rem  = bid & 63;
  const int part = rem >> 4;
  const int rc   = rem & 15;

  const float* yp = A.colPts[task] + batch * NPT * 3;
  const float* xp = A.rowPts[task] + batch * NPT * 3;

  const float inv_eps = 1.0f / A.eps;
  const float sY = inv_eps * KLOG2E;
  const float hc = -8.317766166719343f;   // -ln(4096)
  const int pidxA[4] = {1, 0, 2, 3};
  const int tP = pidxA[task] * 2 + batch;

  const int lane = threadIdx.x & 63;
  const int wave = threadIdx.x >> 6;
  const int q    = lane >> 4;

  // ---- build B fragments (row side), 2 rowsets of 16 rows per wave ----
  const int rowbase = rc * ROWS_PER_BLOCK + wave * 32;
  bf16x8 Bf[2];
#pragma unroll
  for (int rs = 0; rs < 2; ++rs) {
    int i = rowbase + rs * 16 + (lane & 15);
    float X0 = xp[3 * i], X1 = xp[3 * i + 1], X2 = xp[3 * i + 2];
    unsigned short xh0 = f2bf(X0), xh1 = f2bf(X1), xh2 = f2bf(X2);
    unsigned short xl0 = f2bf(X0 - bf2f(xh0));
    unsigned short xl1 = f2bf(X1 - bf2f(xh1));
    unsigned short xl2 = f2bf(X2 - bf2f(xh2));
    short8 bb = (short8)0;
    if (q == 0) {
      short8 t = {(short)xh0, (short)xh1, (short)xh2,
                  (short)xh0, (short)xh1, (short)xh2,
                  (short)xl0, (short)xl1};
      bb = t;
    } else if (q == 1) {
      short8 t = {(short)xl2, (short)0x3F80, (short)0x3F80, (short)0x3F80,
                  (short)xl0, (short)xl1, (short)xl2, 0};
      bb = t;
    }
    Bf[rs] = __builtin_bit_cast(bf16x8, bb);
  }

  // ---- staging: finalize prev-launch potentials + build column A-fragments ----
  for (int c = 0; c < COLS / BLOCK; ++c) {
    int jl = threadIdx.x + c * BLOCK;
    int j  = part * COLS + jl;
    float y0 = yp[3 * j], y1 = yp[3 * j + 1], y2 = yp[3 * j + 2];
    float y2n = 0.5f * (y0 * y0 + y1 * y1 + y2 * y2);
    float pot = 0.0f;
    if (A.usePot) {
      float2 q0 = A.Pprev[(tP * 4 + 0) * NPT + j];
      float2 q1 = A.Pprev[(tP * 4 + 1) * NPT + j];
      float2 q2 = A.Pprev[(tP * 4 + 2) * NPT + j];
      float2 q3 = A.Pprev[(tP * 4 + 3) * NPT + j];
      float M = fmaxf(fmaxf(q0.x, q1.x), fmaxf(q2.x, q3.x));
      float S = q0.y * EXP2(q0.x - M) + q1.y * EXP2(q1.x - M)
              + q2.y * EXP2(q2.x - M) + q3.y * EXP2(q3.x - M);
      float L = M + LOG2(S);
      float r = y2n - A.epsPrev * KLN2 * L;
      if (A.avgPrev) r = 0.5f * (A.Fprev[tP * NPT + j] + r);
      pot = r;
      if (rc == 0) A.Fcur[tP * NPT + j] = pot;
    }
    float T = (hc + (pot - y2n) * inv_eps) * KLOG2E;
    float s0 = y0 * sY, s1 = y1 * sY, s2 = y2 * sY;
    unsigned short yh0 = f2bf(s0), yh1 = f2bf(s1), yh2 = f2bf(s2);
    unsigned short yl0 = f2bf(s0 - bf2f(yh0));
    unsigned short yl1 = f2bf(s1 - bf2f(yh1));
    unsigned short yl2 = f2bf(s2 - bf2f(yh2));
    unsigned short Th = f2bf(T);
    float tr = T - bf2f(Th);
    unsigned short Tm = f2bf(tr);
    tr -= bf2f(Tm);
    unsigned short Tl = f2bf(tr);
    short8 h0 = {(short)yh0, (short)yh1, (short)yh2,
                 (short)yl0, (short)yl1, (short)yl2,
                 (short)yh0, (short)yh1};
    short8 h1 = {(short)yh2, (short)Th, (short)Tm, (short)Tl,
                 (short)yl0, (short)yl1, (short)yl2, 0};
    fragA0[jl] = h0;
    fragA1[jl] = h1;
  }
  __syncthreads();

  // ---- inner loop over 64 column tiles, 2 at a time ----
  const short8* srcA = (lane & 16) ? fragA1 : fragA0;
  const int colsel = lane & 15;
  const f32x4 Z = {0.0f, 0.0f, 0.0f, 0.0f};
  short8 a0s = (short8)0, a1s = (short8)0;   // lanes >=32 stay zero
  float m0 = -__builtin_inff(), s0_ = 0.0f;
  float m1 = -__builtin_inff(), s1_ = 0.0f;

  for (int jt = 0; jt < COLS / 16; jt += 2) {
    if (lane < 32) {
      a0s = srcA[jt * 16 + colsel];
      a1s = srcA[jt * 16 + 16 + colsel];
    }
    bf16x8 A0 = __builtin_bit_cast(bf16x8, a0s);
    bf16x8 A1 = __builtin_bit_cast(bf16x8, a1s);
    f32x4 c00 = __builtin_amdgcn_mfma_f32_16x16x32_bf16(A0, Bf[0], Z, 0, 0, 0);
    f32x4 c10 = __builtin_amdgcn_mfma_f32_16x16x32_bf16(A1, Bf[0], Z, 0, 0, 0);
    f32x4 c01 = __builtin_amdgcn_mfma_f32_16x16x32_bf16(A0, Bf[1], Z, 0, 0, 0);
    f32x4 c11 = __builtin_amdgcn_mfma_f32_16x16x32_bf16(A1, Bf[1], Z, 0, 0, 0);
    lse_merge8(m0, s0_, c00, c10);
    lse_merge8(m1, s1_, c01, c11);
  }

  // ---- cross-quad merge (lanes sharing same row i: xor 16, xor 32) + store partial ----
#pragma unroll
  for (int rs = 0; rs < 2; ++rs) {
    float m = rs ? m1 : m0;
    float s = rs ? s1_ : s0_;
#pragma unroll
    for (int off = 16; off <= 32; off <<= 1) {
      float mo = __shfl_xor(m, off, 64);
      float so = __shfl_xor(s, off, 64);
      float mn = fmaxf(m, mo);
      s = s * EXP2(m - mn) + so * EXP2(mo - mn);
      m = mn;
    }
    if (lane < 16) {
      int i = rowbase + rs * 16 + lane;
      A.Pcur[(tbl * 4 + part) * NPT + i] = make_float2(m, s);
    }
  }
}

// reduce1: finalize last-launch partials, per-row contribution, per-block partial sums
__global__ __launch_bounds__(256) void reduce1(const float2* P, float* R1) {
  int u = blockIdx.x * 256 + threadIdx.x;   // 0..8191
  int b = u >> 12, i = u & 4095;
  float Ls[4];
#pragma unroll
  for (int t = 0; t < 4; ++t) {
    int tbl = t * 2 + b;
    float2 q0 = P[(tbl * 4 + 0) * NPT + i];
    float2 q1 = P[(tbl * 4 + 1) * NPT + i];
    float2 q2 = P[(tbl * 4 + 2) * NPT + i];
    float2 q3 = P[(tbl * 4 + 3) * NPT + i];
    float M = fmaxf(fmaxf(q0.x, q1.x), fmaxf(q2.x, q3.x));
    float S = q0.y * EXP2(q0.x - M) + q1.y * EXP2(q1.x - M)
            + q2.y * EXP2(q2.x - M) + q3.y * EXP2(q3.x - M);
    Ls[t] = M + LOG2(S);
  }
  // (b_x - a_x) + (a_y - b_y) = -eps*ln2*((L0 - L2) + (L1 - L3))
  float acc = (Ls[0] - Ls[2]) + (Ls[1] - Ls[3]);
#pragma unroll
  for (int off = 32; off >= 1; off >>= 1) acc += __shfl_xor(acc, off, 64);
  __shared__ float red[4];
  int wave = threadIdx.x >> 6, lane = threadIdx.x & 63;
  if (lane == 0) red[wave] = acc;
  __syncthreads();
  if (threadIdx.x == 0)
    R1[blockIdx.x] = red[0] + red[1] + red[2] + red[3];
}

__global__ __launch_bounds__(64) void reduce2(const float* R1, float* out) {
  float a = (threadIdx.x < 32) ? R1[threadIdx.x] : 0.0f;
#pragma unroll
  for (int off = 32; off >= 1; off >>= 1) a += __shfl_xor(a, off, 64);
  if (threadIdx.x == 0)
    out[0] = a * (-0.0025f * KLN2 / 4096.0f);
}

extern "C" void kernel_launch(void* const* d_in, const int* in_sizes, int n_in,
                              void* d_out, int out_size, void* d_ws, size_t ws_size,
                              hipStream_t stream) {
  const float* x = (const float*)d_in[0];   // true_data
  const float* y = (const float*)d_in[1];   // particles
  float* out = (float*)d_out;
  float* W = (float*)d_ws;

  float2* P[2] = { (float2*)W, (float2*)(W + 262144) };     // 2 x 1 MB partials
  float*  F[2] = { W + 524288, W + 557056 };                // 2 x 128 KB finalized pots
  float*  R1buf = W + 589824;                               // 32 floats

  // launch schedule: L0 init; L1..9 loop (eps_list); L10 final extrapolation
  static const float epsL[11] = {16.0f, 16.0f, 16.0f, 4.0f, 1.0f, 0.25f, 0.0625f,
                                 0.015625f, 0.00390625f, 0.0025f, 0.0025f};
  static const int avgL[11] = {0, 1, 1, 1, 1, 1, 1, 1, 1, 1, 0};

  const float* rows[4] = { x, y, x, y };   // b_x<-C_xy, a_y<-C_yx, a_x<-C_xx, b_y<-C_yy
  const float* cols[4] = { y, x, x, y };

  dim3 grid(8 * NPARTS * NRC), block(BLOCK);
  for (int L = 0; L <= 10; ++L) {
    SArgs A;
    for (int t = 0; t < 4; ++t) { A.rowPts[t] = rows[t]; A.colPts[t] = cols[t]; }
    A.Pprev = P[(L + 1) & 1];
    A.Pcur  = P[L & 1];
    A.Fprev = F[(L + 1) & 1];
    A.Fcur  = F[L & 1];
    A.eps = epsL[L];
    A.epsPrev = (L > 0) ? epsL[L - 1] : 1.0f;
    A.usePot = (L > 0) ? 1 : 0;
    A.avgPrev = (L > 0) ? avgL[L - 1] : 0;
    softmin_mfma<<<grid, block, 0, stream>>>(A);
  }
  reduce1<<<32, 256, 0, stream>>>(P[0], R1buf);   // L=10 wrote P[10&1]=P[0]
  reduce2<<<1, 64, 0, stream>>>(R1buf, out);
}

// Round 4
// 323.418 us; speedup vs baseline: 8.6943x; 1.1298x over previous
//
#include <hip/hip_runtime.h>

// Sinkhorn divergence (geomloss 'sinkhorn', p=2, blur=0.05, diameter=4, scaling=0.5, debias)
// B=2, N=M=4096, D=3, fp32.
// R4: LSE bookkeeping issue-count cut ~2x: 16-value merges (4 col-tiles, 8 MFMAs per iter),
// v_max3_f32 max trees (fmaxf triples), float2 packed sub/accumulate (v_pk_add_f32).
// MFMA K-slot packing (split-bf16 products + 3-split T against B=1) unchanged from R3 (passed).

typedef __attribute__((ext_vector_type(8))) short short8;
typedef __attribute__((ext_vector_type(8))) __bf16 bf16x8;
typedef __attribute__((ext_vector_type(4))) float f32x4;
typedef __attribute__((ext_vector_type(2))) float f32x2;

#define NPT 4096
#define BLOCK 512
#define COLS 1024           // columns per block (one part)
#define NPARTS 4
#define ROWS_PER_BLOCK 256  // 8 waves x 2 rowsets x 16
#define NRC 16              // rowchunks
#define EXP2 __builtin_amdgcn_exp2f
#define LOG2 __builtin_amdgcn_logf
#define KLOG2E 1.4426950408889634f
#define KLN2 0.6931471805599453f

__device__ inline unsigned short f2bf(float f) {
  unsigned u = __float_as_uint(f);
  return (unsigned short)((u + 0x7FFF + ((u >> 16) & 1)) >> 16);
}
__device__ inline float bf2f(unsigned short h) {
  return __uint_as_float(((unsigned)h) << 16);
}

struct SArgs {
  const float* rowPts[4];
  const float* colPts[4];
  const float2* Pprev;   // partials from previous launch [8 tbl][4 part][4096] (m,s)
  float2* Pcur;
  const float* Fprev;    // finalized potentials [8 tbl][4096]
  float* Fcur;
  float eps, epsPrev;
  int usePot, avgPrev;
};

// merge 16 values into running (m,s); max3-friendly tree + packed f32x2 sub/sum
__device__ inline void lse_merge16(float& m, float& s,
                                   f32x4 c0, f32x4 c1, f32x4 c2, f32x4 c3) {
  float t0 = fmaxf(fmaxf(c0.x, c0.y), c0.z);
  float t1 = fmaxf(fmaxf(c0.w, c1.x), c1.y);
  float t2 = fmaxf(fmaxf(c1.z, c1.w), c2.x);
  float t3 = fmaxf(fmaxf(c2.y, c2.z), c2.w);
  float t4 = fmaxf(fmaxf(c3.x, c3.y), c3.z);
  float u0 = fmaxf(fmaxf(t0, t1), c3.w);
  float u1 = fmaxf(fmaxf(t2, t3), t4);
  float cm = fmaxf(u0, u1);
  float mn = fmaxf(m, cm);
  float sc = EXP2(m - mn);                 // m=-inf first iter -> 0
  f32x2 mn2 = {mn, mn};
  f32x2 sa = {0.0f, 0.0f}, sb = {0.0f, 0.0f};
  f32x2 d;
  d = (f32x2){c0.x, c0.y} - mn2; sa += (f32x2){EXP2(d.x), EXP2(d.y)};
  d = (f32x2){c0.z, c0.w} - mn2; sb += (f32x2){EXP2(d.x), EXP2(d.y)};
  d = (f32x2){c1.x, c1.y} - mn2; sa += (f32x2){EXP2(d.x), EXP2(d.y)};
  d = (f32x2){c1.z, c1.w} - mn2; sb += (f32x2){EXP2(d.x), EXP2(d.y)};
  d = (f32x2){c2.x, c2.y} - mn2; sa += (f32x2){EXP2(d.x), EXP2(d.y)};
  d = (f32x2){c2.z, c2.w} - mn2; sb += (f32x2){EXP2(d.x), EXP2(d.y)};
  d = (f32x2){c3.x, c3.y} - mn2; sa += (f32x2){EXP2(d.x), EXP2(d.y)};
  d = (f32x2){c3.z, c3.w} - mn2; sb += (f32x2){EXP2(d.x), EXP2(d.y)};
  sa += sb;
  s = fmaf(s, sc, sa.x + sa.y);
  m = mn;
}

__global__ __launch_bounds__(BLOCK, 4) void softmin_mfma(SArgs A) {
  __shared__ short8 fragA0[COLS];   // k0..7  per column
  __shared__ short8 fragA1[COLS];   // k8..15 per column

  const int bid  = blockIdx.x;
  const int tbl  = bid >> 6;          // 0..7 = task*2+batch
  const int task = tbl >> 1, batch = tbl & 1;
  const int rem  = bid & 63;
  const int part = rem >> 4;
  const int rc   = rem & 15;

  const float* yp = A.colPts[task] + batch * NPT * 3;
  const float* xp = A.rowPts[task] + batch * NPT * 3;

  const float inv_eps = 1.0f / A.eps;
  const float sY = inv_eps * KLOG2E;
  const float hc = -8.317766166719343f;   // -ln(4096)
  const int pidxA[4] = {1, 0, 2, 3};
  const int tP = pidxA[task] * 2 + batch;

  const int lane = threadIdx.x & 63;
  const int wave = threadIdx.x >> 6;
  const int q    = lane >> 4;

  // ---- build B fragments (row side), 2 rowsets of 16 rows per wave ----
  const int rowbase = rc * ROWS_PER_BLOCK + wave * 32;
  bf16x8 Bf[2];
#pragma unroll
  for (int rs = 0; rs < 2; ++rs) {
    int i = rowbase + rs * 16 + (lane & 15);
    float X0 = xp[3 * i], X1 = xp[3 * i + 1], X2 = xp[3 * i + 2];
    unsigned short xh0 = f2bf(X0), xh1 = f2bf(X1), xh2 = f2bf(X2);
    unsigned short xl0 = f2bf(X0 - bf2f(xh0));
    unsigned short xl1 = f2bf(X1 - bf2f(xh1));
    unsigned short xl2 = f2bf(X2 - bf2f(xh2));
    short8 bb = (short8)0;
    if (q == 0) {
      short8 t = {(short)xh0, (short)xh1, (short)xh2,
                  (short)xh0, (short)xh1, (short)xh2,
                  (short)xl0, (short)xl1};
      bb = t;
    } else if (q == 1) {
      short8 t = {(short)xl2, (short)0x3F80, (short)0x3F80, (short)0x3F80,
                  (short)xl0, (short)xl1, (short)xl2, 0};
      bb = t;
    }
    Bf[rs] = __builtin_bit_cast(bf16x8, bb);
  }

  // ---- staging: finalize prev-launch potentials + build column A-fragments ----
  for (int c = 0; c < COLS / BLOCK; ++c) {
    int jl = threadIdx.x + c * BLOCK;
    int j  = part * COLS + jl;
    float y0 = yp[3 * j], y1 = yp[3 * j + 1], y2 = yp[3 * j + 2];
    float y2n = 0.5f * (y0 * y0 + y1 * y1 + y2 * y2);
    float pot = 0.0f;
    if (A.usePot) {
      float2 q0 = A.Pprev[(tP * 4 + 0) * NPT + j];
      float2 q1 = A.Pprev[(tP * 4 + 1) * NPT + j];
      float2 q2 = A.Pprev[(tP * 4 + 2) * NPT + j];
      float2 q3 = A.Pprev[(tP * 4 + 3) * NPT + j];
      float M = fmaxf(fmaxf(q0.x, q1.x), fmaxf(q2.x, q3.x));
      float S = q0.y * EXP2(q0.x - M) + q1.y * EXP2(q1.x - M)
              + q2.y * EXP2(q2.x - M) + q3.y * EXP2(q3.x - M);
      float L = M + LOG2(S);
      float r = y2n - A.epsPrev * KLN2 * L;
      if (A.avgPrev) r = 0.5f * (A.Fprev[tP * NPT + j] + r);
      pot = r;
      if (rc == 0) A.Fcur[tP * NPT + j] = pot;
    }
    float T = (hc + (pot - y2n) * inv_eps) * KLOG2E;
    float s0 = y0 * sY, s1 = y1 * sY, s2 = y2 * sY;
    unsigned short yh0 = f2bf(s0), yh1 = f2bf(s1), yh2 = f2bf(s2);
    unsigned short yl0 = f2bf(s0 - bf2f(yh0));
    unsigned short yl1 = f2bf(s1 - bf2f(yh1));
    unsigned short yl2 = f2bf(s2 - bf2f(yh2));
    unsigned short Th = f2bf(T);
    float tr = T - bf2f(Th);
    unsigned short Tm = f2bf(tr);
    tr -= bf2f(Tm);
    unsigned short Tl = f2bf(tr);
    short8 h0 = {(short)yh0, (short)yh1, (short)yh2,
                 (short)yl0, (short)yl1, (short)yl2,
                 (short)yh0, (short)yh1};
    short8 h1 = {(short)yh2, (short)Th, (short)Tm, (short)Tl,
                 (short)yl0, (short)yl1, (short)yl2, 0};
    fragA0[jl] = h0;
    fragA1[jl] = h1;
  }
  __syncthreads();

  // ---- inner loop: 4 column tiles (64 cols) per iteration, 8 MFMAs ----
  const short8* srcA = (lane & 16) ? fragA1 : fragA0;
  const int colsel = lane & 15;
  const f32x4 Z = {0.0f, 0.0f, 0.0f, 0.0f};
  short8 as0 = (short8)0, as1 = (short8)0, as2 = (short8)0, as3 = (short8)0;
  float m0 = -__builtin_inff(), s0_ = 0.0f;
  float m1 = -__builtin_inff(), s1_ = 0.0f;

  for (int jt = 0; jt < COLS / 16; jt += 4) {
    if (lane < 32) {
      as0 = srcA[(jt + 0) * 16 + colsel];
      as1 = srcA[(jt + 1) * 16 + colsel];
      as2 = srcA[(jt + 2) * 16 + colsel];
      as3 = srcA[(jt + 3) * 16 + colsel];
    }
    bf16x8 A0 = __builtin_bit_cast(bf16x8, as0);
    bf16x8 A1 = __builtin_bit_cast(bf16x8, as1);
    bf16x8 A2 = __builtin_bit_cast(bf16x8, as2);
    bf16x8 A3 = __builtin_bit_cast(bf16x8, as3);
    f32x4 c00 = __builtin_amdgcn_mfma_f32_16x16x32_bf16(A0, Bf[0], Z, 0, 0, 0);
    f32x4 c01 = __builtin_amdgcn_mfma_f32_16x16x32_bf16(A1, Bf[0], Z, 0, 0, 0);
    f32x4 c02 = __builtin_amdgcn_mfma_f32_16x16x32_bf16(A2, Bf[0], Z, 0, 0, 0);
    f32x4 c03 = __builtin_amdgcn_mfma_f32_16x16x32_bf16(A3, Bf[0], Z, 0, 0, 0);
    f32x4 c10 = __builtin_amdgcn_mfma_f32_16x16x32_bf16(A0, Bf[1], Z, 0, 0, 0);
    f32x4 c11 = __builtin_amdgcn_mfma_f32_16x16x32_bf16(A1, Bf[1], Z, 0, 0, 0);
    f32x4 c12 = __builtin_amdgcn_mfma_f32_16x16x32_bf16(A2, Bf[1], Z, 0, 0, 0);
    f32x4 c13 = __builtin_amdgcn_mfma_f32_16x16x32_bf16(A3, Bf[1], Z, 0, 0, 0);
    lse_merge16(m0, s0_, c00, c01, c02, c03);
    lse_merge16(m1, s1_, c10, c11, c12, c13);
  }

  // ---- cross-quad merge (lanes sharing same row i: xor 16, xor 32) + store partial ----
#pragma unroll
  for (int rs = 0; rs < 2; ++rs) {
    float m = rs ? m1 : m0;
    float s = rs ? s1_ : s0_;
#pragma unroll
    for (int off = 16; off <= 32; off <<= 1) {
      float mo = __shfl_xor(m, off, 64);
      float so = __shfl_xor(s, off, 64);
      float mn = fmaxf(m, mo);
      s = s * EXP2(m - mn) + so * EXP2(mo - mn);
      m = mn;
    }
    if (lane < 16) {
      int i = rowbase + rs * 16 + lane;
      A.Pcur[(tbl * 4 + part) * NPT + i] = make_float2(m, s);
    }
  }
}

// reduce1: finalize last-launch partials, per-row contribution, per-block partial sums
__global__ __launch_bounds__(256) void reduce1(const float2* P, float* R1) {
  int u = blockIdx.x * 256 + threadIdx.x;   // 0..8191
  int b = u >> 12, i = u & 4095;
  float Ls[4];
#pragma unroll
  for (int t = 0; t < 4; ++t) {
    int tbl = t * 2 + b;
    float2 q0 = P[(tbl * 4 + 0) * NPT + i];
    float2 q1 = P[(tbl * 4 + 1) * NPT + i];
    float2 q2 = P[(tbl * 4 + 2) * NPT + i];
    float2 q3 = P[(tbl * 4 + 3) * NPT + i];
    float M = fmaxf(fmaxf(q0.x, q1.x), fmaxf(q2.x, q3.x));
    float S = q0.y * EXP2(q0.x - M) + q1.y * EXP2(q1.x - M)
            + q2.y * EXP2(q2.x - M) + q3.y * EXP2(q3.x - M);
    Ls[t] = M + LOG2(S);
  }
  // (b_x - a_x) + (a_y - b_y) = -eps*ln2*((L0 - L2) + (L1 - L3))
  float acc = (Ls[0] - Ls[2]) + (Ls[1] - Ls[3]);
#pragma unroll
  for (int off = 32; off >= 1; off >>= 1) acc += __shfl_xor(acc, off, 64);
  __shared__ float red[4];
  int wave = threadIdx.x >> 6, lane = threadIdx.x & 63;
  if (lane == 0) red[wave] = acc;
  __syncthreads();
  if (threadIdx.x == 0)
    R1[blockIdx.x] = red[0] + red[1] + red[2] + red[3];
}

__global__ __launch_bounds__(64) void reduce2(const float* R1, float* out) {
  float a = (threadIdx.x < 32) ? R1[threadIdx.x] : 0.0f;
#pragma unroll
  for (int off = 32; off >= 1; off >>= 1) a += __shfl_xor(a, off, 64);
  if (threadIdx.x == 0)
    out[0] = a * (-0.0025f * KLN2 / 4096.0f);
}

extern "C" void kernel_launch(void* const* d_in, const int* in_sizes, int n_in,
                              void* d_out, int out_size, void* d_ws, size_t ws_size,
                              hipStream_t stream) {
  const float* x = (const float*)d_in[0];   // true_data
  const float* y = (const float*)d_in[1];   // particles
  float* out = (float*)d_out;
  float* W = (float*)d_ws;

  float2* P[2] = { (float2*)W, (float2*)(W + 262144) };     // 2 x 1 MB partials
  float*  F[2] = { W + 524288, W + 557056 };                // 2 x 128 KB finalized pots
  float*  R1buf = W + 589824;                               // 32 floats

  // launch schedule: L0 init; L1..9 loop (eps_list); L10 final extrapolation
  static const float epsL[11] = {16.0f, 16.0f, 16.0f, 4.0f, 1.0f, 0.25f, 0.0625f,
                                 0.015625f, 0.00390625f, 0.0025f, 0.0025f};
  static const int avgL[11] = {0, 1, 1, 1, 1, 1, 1, 1, 1, 1, 0};

  const float* rows[4] = { x, y, x, y };   // b_x<-C_xy, a_y<-C_yx, a_x<-C_xx, b_y<-C_yy
  const float* cols[4] = { y, x, x, y };

  dim3 grid(8 * NPARTS * NRC), block(BLOCK);
  for (int L = 0; L <= 10; ++L) {
    SArgs A;
    for (int t = 0; t < 4; ++t) { A.rowPts[t] = rows[t]; A.colPts[t] = cols[t]; }
    A.Pprev = P[(L + 1) & 1];
    A.Pcur  = P[L & 1];
    A.Fprev = F[(L + 1) & 1];
    A.Fcur  = F[L & 1];
    A.eps = epsL[L];
    A.epsPrev = (L > 0) ? epsL[L - 1] : 1.0f;
    A.usePot = (L > 0) ? 1 : 0;
    A.avgPrev = (L > 0) ? avgL[L - 1] : 0;
    softmin_mfma<<<grid, block, 0, stream>>>(A);
  }
  reduce1<<<32, 256, 0, stream>>>(P[0], R1buf);   // L=10 wrote P[10&1]=P[0]
  reduce2<<<1, 64, 0, stream>>>(R1buf, out);
}